// Round 4
// baseline (367.910 us; speedup 1.0000x reference)
//
#include <hip/hip_runtime.h>
#include <math.h>

#define NB 8          // batch
#define NQH 32
#define NKVH 8
#define HD 128
#define GQ 4          // q heads per kv head
#define T_PAST 4085   // past tokens handled by attn_partial
#define SPLITS 32
#define TCHUNK 128
#define PPAD 130      // partial row: 128 acc + l + spare
#define BPS 289       // blocks per sequence in block_tables
#define LOG2_10K_OVER_64 0.2076205059304601f
#define SCALE 0.08838834764831843f  // 1/sqrt(128)
#define LOG2E 1.4426950408889634f

// ws layout (floats)
#define PART_ATTN_OFF 0
#define PART_ATTN_SZ  (64 * GQ * SPLITS * PPAD)     // 1,064,960
#define ATTN_OFF      PART_ATTN_SZ

// sin/cos of freq = pos*inv_j (f32 mul, same rounding as the table version),
// with Cody-Waite 3-term reduction so large freqs keep ~1e-6 rad accuracy.
__device__ __forceinline__ void rope_cs_inv(float posf, float inv, float& cs, float& sn)
{
    const float INV2PI = 0.15915494309189535f;
    const float P1 = 6.28125f;                   // 201*2^-5 (exact, 8-bit)
    const float P2 = 0.0019354820251464844f;     // 4059*2^-21 (exact, 12-bit)
    const float P3 = -1.748455600075e-7f;        // 2pi - P1 - P2
    float freq = posf * inv;                      // matches reference f32 rounding
    float n    = rintf(freq * INV2PI);            // n <= 652
    float red  = fmaf(-n, P1, freq);              // exact
    red        = fmaf(-n, P2, red);               // exact product
    red        = fmaf(-n, P3, red);
    float rev  = red * INV2PI;                    // [-0.5, 0.5] revolutions
    sn = __builtin_amdgcn_sinf(rev);
    cs = __builtin_amdgcn_cosf(rev);
}

__device__ __forceinline__ void rope_cs(float posf, int j, float& cs, float& sn)
{
    float inv = __builtin_amdgcn_exp2f(-(float)j * LOG2_10K_OVER_64);
    rope_cs_inv(posf, inv, cs, sn);
}

// Wave-autonomous decode attention. Each wave owns 32 tokens; K/V stream
// global->registers (no K/V LDS, no intra-tile barriers). Lane layout:
// hl=lane&31 owns dims {2hl,2hl+1,2hl+64,2hl+65}; half=lane>>5 picks token
// A/B of each pair. Scores reduce via 5-level shfl_xor within the 32-lane
// half. Q pre-roped+scaled in registers. Ping-pong 1-ahead prefetch: with
// no barriers, the compiler's native counted-vmcnt scoreboarding overlaps
// loads with the previous token-pair's compute. One final __syncthreads
// for the 4-wave LDS reduce (keeps part at 32 splits, ws unchanged).
__global__ __launch_bounds__(256) void attn_partial_kernel(
    const float* __restrict__ q,
    const int* __restrict__ bt, const float* __restrict__ kc, const float* __restrict__ vc,
    float* __restrict__ part)
{
    __shared__ float red[4][GQ][128];     // per-wave acc for final reduce
    __shared__ float lredb[4][GQ];

    const int tid  = threadIdx.x;
    const int bh   = blockIdx.x;          // 0..63 (b, kv-head)
    const int s    = blockIdx.y;          // 0..31
    const int b    = bh >> 3, h = bh & 7;
    const int lane = tid & 63, w = tid >> 6;
    const int hl   = lane & 31;           // dim-lane within half
    const int half = lane >> 5;           // token A/B selector
    const int t0w  = s * TCHUNK + w * 32; // this wave's token base
    const int* btb = bt + b * BPS;

    // ---- per-lane token offset/pos (lanes 32-63 duplicate 0-31) ----
    unsigned int offv = 0u; int posv = 0;
    {
        int tokl = t0w + hl;
        if (tokl < T_PAST) {
            int bti, rr;
            if (tokl < 16)        { bti = 0;                rr = tokl;        }
            else if (tokl < 4080) { bti = 33 + (tokl >> 4); rr = tokl & 15;   }
            else                  { bti = 288;              rr = tokl - 4080; }
            offv = (unsigned int)(((btb[bti] * 16 + rr) * NKVH + h) * HD);
            posv = (tokl < 16) ? tokl : tokl + 10;
        }
    }

    // ---- RoPE inverse freqs for this lane's dim pair (j = 2hl, 2hl+1) ----
    const float inv0 = __builtin_amdgcn_exp2f(-(float)(2 * hl)     * LOG2_10K_OVER_64);
    const float inv1 = __builtin_amdgcn_exp2f(-(float)(2 * hl + 1) * LOG2_10K_OVER_64);

    // ---- Q: load, rope at 4095, pre-scale; 16 regs ----
    float2 qa[GQ], qb[GQ];
    {
        const float* qbase = q + (size_t)b * (NQH * HD) + (size_t)h * (GQ * HD);
        float cq0, sq0, cq1, sq1;
        rope_cs_inv(4095.0f, inv0, cq0, sq0);
        rope_cs_inv(4095.0f, inv1, cq1, sq1);
        #pragma unroll
        for (int g = 0; g < GQ; ++g) {
            float2 xa = *(const float2*)(qbase + g * HD + 2 * hl);
            float2 xb = *(const float2*)(qbase + g * HD + 2 * hl + 64);
            qa[g].x = (xa.x * cq0 - xb.x * sq0) * SCALE;
            qb[g].x = (xb.x * cq0 + xa.x * sq0) * SCALE;
            qa[g].y = (xa.y * cq1 - xb.y * sq1) * SCALE;
            qb[g].y = (xb.y * cq1 + xa.y * sq1) * SCALE;
        }
    }

    float2 accl[GQ] = {}, acch[GQ] = {};
    float  lr[GQ]   = {};

    // token-pair body: compute with CUR regs (token 2I+half), prefetch NI pair
#define AB_BODY(K1C,K2C,V1C,V2C, K1N,K2N,V1N,V2N, I, NI)                      \
    {                                                                          \
        unsigned int noff_ = __shfl(offv, 2 * (NI) + half);                    \
        const float* kn_ = kc + noff_ + 2 * hl;                                \
        const float* vn_ = vc + noff_ + 2 * hl;                                \
        K1N = *(const float2*)kn_;        K2N = *(const float2*)(kn_ + 64);    \
        V1N = *(const float2*)vn_;        V2N = *(const float2*)(vn_ + 64);    \
        float posf_ = (float)__shfl(posv, 2 * (I) + half);                     \
        float cs0_, sn0_, cs1_, sn1_;                                          \
        rope_cs_inv(posf_, inv0, cs0_, sn0_);                                  \
        rope_cs_inv(posf_, inv1, cs1_, sn1_);                                  \
        float r1x_ = K1C.x * cs0_ - K2C.x * sn0_;                              \
        float r2x_ = K2C.x * cs0_ + K1C.x * sn0_;                              \
        float r1y_ = K1C.y * cs1_ - K2C.y * sn1_;                              \
        float r2y_ = K2C.y * cs1_ + K1C.y * sn1_;                              \
        float d_[GQ];                                                          \
        _Pragma("unroll")                                                      \
        for (int g = 0; g < GQ; ++g)                                           \
            d_[g] = r1x_ * qa[g].x + r1y_ * qa[g].y                            \
                  + r2x_ * qb[g].x + r2y_ * qb[g].y;                           \
        _Pragma("unroll")                                                      \
        for (int m_ = 1; m_ <= 16; m_ <<= 1) {                                 \
            _Pragma("unroll")                                                  \
            for (int g = 0; g < GQ; ++g) d_[g] += __shfl_xor(d_[g], m_);       \
        }                                                                      \
        bool valid_ = (t0w + 2 * (I) + half) < T_PAST;                         \
        _Pragma("unroll")                                                      \
        for (int g = 0; g < GQ; ++g) {                                         \
            float p_ = valid_ ? __builtin_amdgcn_exp2f(d_[g] * LOG2E) : 0.f;   \
            lr[g] += p_;                                                       \
            accl[g].x = fmaf(p_, V1C.x, accl[g].x);                            \
            accl[g].y = fmaf(p_, V1C.y, accl[g].y);                            \
            acch[g].x = fmaf(p_, V2C.x, acch[g].x);                            \
            acch[g].y = fmaf(p_, V2C.y, acch[g].y);                            \
        }                                                                      \
    }

    float2 k1a, k2a, v1a, v2a, k1b, k2b, v1b, v2b;
    // prologue: load pair 0 into A set
    {
        unsigned int off0 = __shfl(offv, half);
        const float* kp = kc + off0 + 2 * hl;
        const float* vp = vc + off0 + 2 * hl;
        k1a = *(const float2*)kp;       k2a = *(const float2*)(kp + 64);
        v1a = *(const float2*)vp;       v2a = *(const float2*)(vp + 64);
    }

    #pragma unroll 1
    for (int i = 0; i < 16; i += 2) {
        AB_BODY(k1a, k2a, v1a, v2a, k1b, k2b, v1b, v2b, i, i + 1);
        int ni2 = (i + 2 < 16) ? i + 2 : 15;   // tail: harmless reload
        AB_BODY(k1b, k2b, v1b, v2b, k1a, k2a, v1a, v2a, i + 1, ni2);
    }
#undef AB_BODY

    // ---- cross-half sum (token A-half + B-half) ----
    #pragma unroll
    for (int g = 0; g < GQ; ++g) {
        accl[g].x += __shfl_xor(accl[g].x, 32);
        accl[g].y += __shfl_xor(accl[g].y, 32);
        acch[g].x += __shfl_xor(acch[g].x, 32);
        acch[g].y += __shfl_xor(acch[g].y, 32);
        lr[g]     += __shfl_xor(lr[g], 32);
    }

    // ---- 4-wave LDS reduce (the only barrier in the kernel) ----
    #pragma unroll
    for (int g = 0; g < GQ; ++g) {
        float2 st = (half == 0) ? accl[g] : acch[g];
        *(float2*)&red[w][g][2 * hl + half * 64] = st;
    }
    if (lane == 0) {
        #pragma unroll
        for (int g = 0; g < GQ; ++g) lredb[w][g] = lr[g];
    }
    __syncthreads();

    for (int e = tid; e < GQ * 128; e += 256) {
        int g = e >> 7, d = e & 127;
        float sum = red[0][g][d] + red[1][g][d] + red[2][g][d] + red[3][g][d];
        part[((size_t)(bh * GQ + g) * SPLITS + s) * PPAD + d] = sum;
    }
    if (tid < GQ) {
        float l = lredb[0][tid] + lredb[1][tid] + lredb[2][tid] + lredb[3][tid];
        part[((size_t)(bh * GQ + tid) * SPLITS + s) * PPAD + 129] = l;
    }
}

// Folds the current-token contribution (score recomputed here, V un-roped)
// into the split reduction, and zeroes `out` for gemm's atomic accumulation.
__global__ __launch_bounds__(256) void attn_reduce_kernel(
    const float* __restrict__ part,
    const float* __restrict__ q, const float* __restrict__ k, const float* __restrict__ v,
    float* __restrict__ attn, float* __restrict__ out)
{
    int bh = blockIdx.x;
    int tid = threadIdx.x;
    int g = tid >> 6, lane = tid & 63;
    int b = bh >> 3, h = bh & 7;

    // zero out (8*4096 floats over 64 blocks * 256 threads: float2 each)
    *(float2*)(out + (size_t)(bh * 256 + tid) * 2) = make_float2(0.f, 0.f);

    // current-token score for (b, h, g): dims j=lane and j+64 per lane
    const float* qp = q + (size_t)b * (NQH * HD) + (size_t)(h * GQ + g) * HD;
    const float* kp = k + (size_t)(b * NKVH + h) * HD;
    float cs, sn; rope_cs(4095.0f, lane, cs, sn);
    float q1 = qp[lane], q2 = qp[lane + 64];
    float k1 = kp[lane], k2 = kp[lane + 64];
    float qr1 = q1*cs - q2*sn, qr2 = q2*cs + q1*sn;
    float kr1 = k1*cs - k2*sn, kr2 = k2*cs + k1*sn;
    float dot = qr1*kr1 + qr2*kr2;
    dot += __shfl_xor(dot, 1);  dot += __shfl_xor(dot, 2);
    dot += __shfl_xor(dot, 4);  dot += __shfl_xor(dot, 8);
    dot += __shfl_xor(dot, 16); dot += __shfl_xor(dot, 32);
    float p_cur = __builtin_amdgcn_exp2f(dot * SCALE * LOG2E);

    const float* pg = part + (size_t)(bh * GQ + g) * SPLITS * PPAD;
    float accl = 0.f, acch = 0.f, l = 0.f;
    #pragma unroll 8
    for (int s = 0; s < SPLITS; ++s) {
        l    += pg[s * PPAD + 129];
        accl += pg[s * PPAD + lane];
        acch += pg[s * PPAD + lane + 64];
    }
    const float* vp = v + (size_t)(b * NKVH + h) * HD;
    accl += p_cur * vp[lane];
    acch += p_cur * vp[lane + 64];
    l += p_cur;
    float inv_l = 1.0f / l;
    size_t base = (size_t)b * 4096 + (size_t)(h * GQ + g) * 128;
    attn[base + lane]      = accl * inv_l;
    attn[base + lane + 64] = acch * inv_l;
}

// grid (32 col-stripes of 128, 16 K-splits of 256); 4 waves split rows 64-way
// each. Split-K partials accumulate straight into `out` via atomicAdd
// (out zeroed by attn_reduce, stream-ordered).
__global__ __launch_bounds__(256) void gemm_partial_kernel(
    const float* __restrict__ attn, const float* __restrict__ Wo,
    float* __restrict__ out)
{
    __shared__ float a_s[NB][256];
    __shared__ float red[4][NB][128];
    int tid = threadIdx.x;
    int lane = tid & 63, w = tid >> 6;
    int jt = blockIdx.x;      // 0..31
    int is = blockIdx.y;      // 0..15
    int i0 = is * 256;
    int c  = jt * 128 + lane * 2;
    for (int e = tid; e < NB * 256; e += 256) {
        int bb = e >> 8, i = e & 255;
        a_s[bb][i] = attn[(size_t)bb * 4096 + i0 + i];
    }
    __syncthreads();
    float accx[NB] = {}, accy[NB] = {};
    const float* wp = Wo + (size_t)(i0 + w * 64) * 4096 + c;
    #pragma unroll 8
    for (int ii = 0; ii < 64; ++ii) {
        float2 wv = *(const float2*)(wp + (size_t)ii * 4096);
        int il = w * 64 + ii;
        #pragma unroll
        for (int bb = 0; bb < NB; ++bb) {
            float a = a_s[bb][il];
            accx[bb] += a * wv.x;
            accy[bb] += a * wv.y;
        }
    }
    #pragma unroll
    for (int bb = 0; bb < NB; ++bb) {
        red[w][bb][lane * 2]     = accx[bb];
        red[w][bb][lane * 2 + 1] = accy[bb];
    }
    __syncthreads();
    for (int e = tid; e < NB * 128; e += 256) {
        int bb = e >> 7, l = e & 127;
        float sum = red[0][bb][l] + red[1][bb][l] + red[2][bb][l] + red[3][bb][l];
        atomicAdd(&out[(size_t)bb * 4096 + jt * 128 + l], sum);
    }
}

extern "C" void kernel_launch(void* const* d_in, const int* in_sizes, int n_in,
                              void* d_out, int out_size, void* d_ws, size_t ws_size,
                              hipStream_t stream) {
    const float* q  = (const float*)d_in[0];
    const float* k  = (const float*)d_in[1];
    const float* v  = (const float*)d_in[2];
    const int*   bt = (const int*)d_in[5];
    const float* kc = (const float*)d_in[6];
    const float* vc = (const float*)d_in[7];
    const float* Wo = (const float*)d_in[8];
    float* out = (float*)d_out;
    float* ws  = (float*)d_ws;

    float* part_attn = ws + PART_ATTN_OFF;
    float* attn      = ws + ATTN_OFF;

    attn_partial_kernel<<<dim3(64, SPLITS), 256, 0, stream>>>(q, bt, kc, vc, part_attn);
    attn_reduce_kernel<<<64, 256, 0, stream>>>(part_attn, q, k, v, attn, out);
    gemm_partial_kernel<<<dim3(32, 16), 256, 0, stream>>>(attn, Wo, out);
}